// Round 6
// baseline (89.511 us; speedup 1.0000x reference)
//
#include <hip/hip_runtime.h>
#include <hip/hip_bf16.h>

// CharRNN: B=16384, T=100, V=256, E=50, H=10, L=15 — float tensors fp32.
// R6: latency attack on the recurrence. At 1 wave/SIMD nothing hides the
// dependent chain; R5's 12-term serial FMA accumulate (48 cyc) + tanh chain
// (~20 cyc) explains the observed ~105 cyc/step vs ~66 issue-bound. Split
// each accumulator into two independent 6-term chains (m={0,1} vs m={2,3})
// + one combine add: dependent path 48 -> 28 cyc/step. Also prefetch
// drop/bd ahead of the loop to bury epilogue load latency.

#define Bn 16384
#define Tn 100
#define Vn 256
#define En 50
#define Hn 10
#define Ln 15
#define PROW 12  // padded hidden dim (4 lanes x 3 units)
#define LAMBDA 2.8853900817779268f  // 2/ln2, folded into P and Wh

typedef float v2f __attribute__((ext_vector_type(2)));

// quad_perm DPP controls: xor1={1,0,3,2}, xor2={2,3,0,1}, xor3={3,2,1,0}
#define QP_X1 0xB1
#define QP_X2 0x4E
#define QP_X3 0x1B
#define DPPF(v, ctrl) \
    __int_as_float(__builtin_amdgcn_mov_dpp(__float_as_int(v), (ctrl), 0xF, 0xF, true))

// Input pre-scaled by LAMBDA: tanh(x) = 1 - 2/(exp2(lambda*x) + 1).
// No clamp: exp2(+big)=inf -> rcp=0 -> +1; exp2(-big)=0 -> rcp(1)=1 -> -1.
__device__ __forceinline__ float tanh_scaled(float xs) {
    float e = __builtin_amdgcn_exp2f(xs);
    float r = __builtin_amdgcn_rcpf(e + 1.f);
    return __builtin_fmaf(-2.f, r, 1.f);
}

__global__ __launch_bounds__(256) void rnn_fused(
    const int* __restrict__ x,
    const float* __restrict__ emb,
    const float* __restrict__ Wx,
    const float* __restrict__ b_rnn,
    const float* __restrict__ Wh,
    const float* __restrict__ Wd,
    const float* __restrict__ bd,
    const float* __restrict__ drop,
    float* __restrict__ out) {
    __shared__ float embL[Vn * En];  // 51.2 KB
    __shared__ float Pl[Vn * PROW];  // 12 KB

    const int tid = threadIdx.x;

    // ---- Stage emb (coalesced float4: 3200 x 16B over 256 threads) ----
    {
        const float4* Eg = (const float4*)emb;
        float4* Es = (float4*)embL;
        #pragma unroll
        for (int i = 0; i < 13; ++i) {
            int idx = i * 256 + tid;
            if (idx < (Vn * En) / 4) Es[idx] = Eg[idx];
        }
    }
    __syncthreads();

    // ---- Phase A: thread v computes P row v into Pl (Wx/b_rnn via SGPR) ----
    {
        const int v = tid;
        v2f acc[5];
        #pragma unroll
        for (int j2 = 0; j2 < 5; ++j2) {
            v2f a; a.x = b_rnn[2 * j2]; a.y = b_rnn[2 * j2 + 1];
            acc[j2] = a;
        }
        const v2f* er = (const v2f*)(embL + v * En);  // 25 x float2, 8B aligned
        #pragma unroll 5
        for (int k2 = 0; k2 < En / 2; ++k2) {
            v2f e2 = er[k2];
            v2f ex = {e2.x, e2.x}, ey = {e2.y, e2.y};
            #pragma unroll
            for (int j2 = 0; j2 < 5; ++j2) {
                v2f w0; w0.x = Wx[(2 * k2) * Hn + 2 * j2];     w0.y = Wx[(2 * k2) * Hn + 2 * j2 + 1];
                v2f w1; w1.x = Wx[(2 * k2 + 1) * Hn + 2 * j2]; w1.y = Wx[(2 * k2 + 1) * Hn + 2 * j2 + 1];
                acc[j2] += ex * w0;
                acc[j2] += ey * w1;
            }
        }
        float* Pr = Pl + v * PROW;
        #pragma unroll
        for (int j2 = 0; j2 < 5; ++j2) {
            Pr[2 * j2]     = acc[j2].x * LAMBDA;  // lambda folded into P
            Pr[2 * j2 + 1] = acc[j2].y * LAMBDA;
        }
        Pr[10] = 0.f;
        Pr[11] = 0.f;
    }

    // ---- Per-lane Wh fragments (L2-resident scalar loads), x LAMBDA ----
    const int g  = blockIdx.x * 256 + tid;
    const int b  = g >> 2;   // batch element
    const int q  = g & 3;    // quad sub-lane
    const int j0 = 3 * q;    // first owned hidden unit

    v2f   whv[4][3];
    float whs[4][3];
    #pragma unroll
    for (int m = 0; m < 4; ++m) {
        int qs = q ^ m;
        #pragma unroll
        for (int rp = 0; rp < 3; ++rp) {
            int js  = 3 * qs + rp;
            int jss = js < Hn ? js : 0;  // safe address, value zeroed below
            float w0 = Wh[jss * Hn + (j0 + 0 < Hn ? j0 + 0 : 0)];
            float w1 = Wh[jss * Hn + (j0 + 1 < Hn ? j0 + 1 : 0)];
            float w2 = Wh[jss * Hn + (j0 + 2 < Hn ? j0 + 2 : 0)];
            bool oks = js < Hn;
            v2f wv;
            wv.x = (oks && j0 + 0 < Hn) ? w0 * LAMBDA : 0.f;
            wv.y = (oks && j0 + 1 < Hn) ? w1 * LAMBDA : 0.f;
            whv[m][rp] = wv;
            whs[m][rp] = (oks && j0 + 2 < Hn) ? w2 * LAMBDA : 0.f;
        }
    }

    // Prefetch epilogue constants (independent of the loop).
    float dpre[3];
    #pragma unroll
    for (int r = 0; r < 3; ++r) {
        int j = j0 + r;
        dpre[r] = drop[b * Hn + (j < Hn ? j : Hn - 1)];
    }
    const int l0 = q * 4;
    float bdpre[4];
    #pragma unroll
    for (int li = 0; li < 4; ++li)
        bdpre[li] = bd[(l0 + li < Ln) ? l0 + li : Ln - 1];

    __syncthreads();

    // ---- Phase B: the recurrence ----
    const int* xb = x + b * Tn;  // 400 B/row -> 16B aligned

    v2f   hv = {0.f, 0.f};  // owned h: j0, j0+1
    float hs = 0.f;         // owned h: j0+2

    int4 xi = *(const int4*)xb;
    for (int c = 0; c < Tn / 4; ++c) {
        int4 xin = (c + 1 < Tn / 4) ? ((const int4*)xb)[c + 1] : xi;
        int xs[4] = {xi.x, xi.y, xi.z, xi.w};
        #pragma unroll
        for (int u = 0; u < 4; ++u) {
            const float* Pr = &Pl[xs[u] * PROW + j0];
            v2f pva, pvb = {0.f, 0.f};
            pva.x = Pr[0];
            pva.y = Pr[1];
            float psa = Pr[2], psb = 0.f;

            // Gather the full h vector from the quad via DPP (9 ops).
            float hsrc[4][3];
            hsrc[0][0] = hv.x;              hsrc[0][1] = hv.y;              hsrc[0][2] = hs;
            hsrc[1][0] = DPPF(hv.x, QP_X1); hsrc[1][1] = DPPF(hv.y, QP_X1); hsrc[1][2] = DPPF(hs, QP_X1);
            hsrc[2][0] = DPPF(hv.x, QP_X2); hsrc[2][1] = DPPF(hv.y, QP_X2); hsrc[2][2] = DPPF(hs, QP_X2);
            hsrc[3][0] = DPPF(hv.x, QP_X3); hsrc[3][1] = DPPF(hv.y, QP_X3); hsrc[3][2] = DPPF(hs, QP_X3);

            // Two independent 6-term chains per accumulator (latency tree).
            #pragma unroll
            for (int rp = 0; rp < 3; ++rp) {
                v2f hb0 = {hsrc[0][rp], hsrc[0][rp]};
                v2f hb1 = {hsrc[1][rp], hsrc[1][rp]};
                pva += hb0 * whv[0][rp];
                pva += hb1 * whv[1][rp];
                psa = __builtin_fmaf(hsrc[0][rp], whs[0][rp], psa);
                psa = __builtin_fmaf(hsrc[1][rp], whs[1][rp], psa);
            }
            #pragma unroll
            for (int rp = 0; rp < 3; ++rp) {
                v2f hb2 = {hsrc[2][rp], hsrc[2][rp]};
                v2f hb3 = {hsrc[3][rp], hsrc[3][rp]};
                pvb += hb2 * whv[2][rp];
                pvb += hb3 * whv[3][rp];
                psb = __builtin_fmaf(hsrc[2][rp], whs[2][rp], psb);
                psb = __builtin_fmaf(hsrc[3][rp], whs[3][rp], psb);
            }
            v2f pv = pva + pvb;
            float ps = psa + psb;

            hv.x = tanh_scaled(pv.x);
            hv.y = tanh_scaled(pv.y);
            hs   = tanh_scaled(ps);
        }
        xi = xin;
    }

    // ---- Epilogue: dropout, quad-gather hd, dense over this lane's l-slice ----
    float hd[3];
    {
        float hown[3] = {hv.x, hv.y, hs};
        #pragma unroll
        for (int r = 0; r < 3; ++r)
            hd[r] = (j0 + r < Hn) ? hown[r] * dpre[r] : 0.f;
    }
    float hdsrc[4][3];
    hdsrc[0][0] = hd[0];              hdsrc[0][1] = hd[1];              hdsrc[0][2] = hd[2];
    hdsrc[1][0] = DPPF(hd[0], QP_X1); hdsrc[1][1] = DPPF(hd[1], QP_X1); hdsrc[1][2] = DPPF(hd[2], QP_X1);
    hdsrc[2][0] = DPPF(hd[0], QP_X2); hdsrc[2][1] = DPPF(hd[1], QP_X2); hdsrc[2][2] = DPPF(hd[2], QP_X2);
    hdsrc[3][0] = DPPF(hd[0], QP_X3); hdsrc[3][1] = DPPF(hd[1], QP_X3); hdsrc[3][2] = DPPF(hd[2], QP_X3);

    const int lcnt = (q == 3) ? 3 : 4;
    #pragma unroll
    for (int li = 0; li < 4; ++li) {
        if (li >= lcnt) break;
        int l = l0 + li;
        float acc = bdpre[li];
        #pragma unroll
        for (int m = 0; m < 4; ++m)
            #pragma unroll
            for (int rp = 0; rp < 3; ++rp) {
                int js  = 3 * (q ^ m) + rp;
                int jss = js < Hn ? js : 0;  // hdsrc is 0 for pads
                acc = __builtin_fmaf(hdsrc[m][rp], Wd[jss * Ln + l], acc);
            }
        out[b * Ln + l] = acc;
    }
}

extern "C" void kernel_launch(void* const* d_in, const int* in_sizes, int n_in,
                              void* d_out, int out_size, void* d_ws, size_t ws_size,
                              hipStream_t stream) {
    const int*   x      = (const int*)d_in[0];
    const float* emb    = (const float*)d_in[1];
    const float* Wx     = (const float*)d_in[2];
    const float* Wh     = (const float*)d_in[3];
    const float* b_rnn  = (const float*)d_in[4];
    const float* Wd     = (const float*)d_in[5];
    const float* bd     = (const float*)d_in[6];
    const float* drop   = (const float*)d_in[7];
    float*       out    = (float*)d_out;
    (void)d_ws; (void)ws_size;

    // 65536 lanes / 256 = 256 blocks -> 1 block/CU, 4 waves -> 1 wave/SIMD.
    rnn_fused<<<(Bn * 4) / 256, 256, 0, stream>>>(x, emb, Wx, b_rnn, Wh, Wd, bd, drop, out);
}

// Round 7
// 88.420 us; speedup vs baseline: 1.0123x; 1.0123x over previous
//
#include <hip/hip_runtime.h>
#include <hip/hip_bf16.h>

// CharRNN: B=16384, T=100, V=256, E=50, H=10, L=15 — float tensors fp32.
// R7 = revert to R5 (best measured: 87.4 us). R6's latency-split regressed:
// the recurrence is VALU-issue-bound (~40 full-rate instr/step ~= 80-90 cyc
// issue vs ~105 observed incl. trans overlap), not dependency-bound.
// Structure: fused single kernel.
//  Phase A: stage emb in LDS (float4), P[v][j] = emb[v]·Wx[:,j] + b_rnn[j]
//           computed per-thread with Wx/b_rnn via wave-uniform SGPR loads,
//           lambda = 2/ln2 folded into P and Wh fragments.
//  Phase B: quad-lane recurrence — 4 lanes per batch element, 3 hidden
//           units each (PROW=12 zero-padded), h-exchange via DPP quad_perm,
//           tanh via exp2+rcp (saturates correctly, no clamp).
// 1024 waves -> 1 wave on each of the 1024 SIMDs; ~5 us kernel against an
// ~82 us harness ws-re-poison floor.

#define Bn 16384
#define Tn 100
#define Vn 256
#define En 50
#define Hn 10
#define Ln 15
#define PROW 12  // padded hidden dim (4 lanes x 3 units)
#define LAMBDA 2.8853900817779268f  // 2/ln2, folded into P and Wh

typedef float v2f __attribute__((ext_vector_type(2)));

// quad_perm DPP controls: xor1={1,0,3,2}, xor2={2,3,0,1}, xor3={3,2,1,0}
#define QP_X1 0xB1
#define QP_X2 0x4E
#define QP_X3 0x1B
#define DPPF(v, ctrl) \
    __int_as_float(__builtin_amdgcn_mov_dpp(__float_as_int(v), (ctrl), 0xF, 0xF, true))

// Input pre-scaled by LAMBDA: tanh(x) = 1 - 2/(exp2(lambda*x) + 1).
// No clamp: exp2(+big)=inf -> rcp=0 -> +1; exp2(-big)=0 -> rcp(1)=1 -> -1.
__device__ __forceinline__ float tanh_scaled(float xs) {
    float e = __builtin_amdgcn_exp2f(xs);
    float r = __builtin_amdgcn_rcpf(e + 1.f);
    return __builtin_fmaf(-2.f, r, 1.f);
}

__global__ __launch_bounds__(256) void rnn_fused(
    const int* __restrict__ x,
    const float* __restrict__ emb,
    const float* __restrict__ Wx,
    const float* __restrict__ b_rnn,
    const float* __restrict__ Wh,
    const float* __restrict__ Wd,
    const float* __restrict__ bd,
    const float* __restrict__ drop,
    float* __restrict__ out) {
    __shared__ float embL[Vn * En];  // 51.2 KB
    __shared__ float Pl[Vn * PROW];  // 12 KB

    const int tid = threadIdx.x;

    // ---- Stage emb (coalesced float4: 3200 x 16B over 256 threads) ----
    {
        const float4* Eg = (const float4*)emb;
        float4* Es = (float4*)embL;
        #pragma unroll
        for (int i = 0; i < 13; ++i) {
            int idx = i * 256 + tid;
            if (idx < (Vn * En) / 4) Es[idx] = Eg[idx];
        }
    }
    __syncthreads();

    // ---- Phase A: thread v computes P row v into Pl (Wx/b_rnn via SGPR) ----
    {
        const int v = tid;
        v2f acc[5];
        #pragma unroll
        for (int j2 = 0; j2 < 5; ++j2) {
            v2f a; a.x = b_rnn[2 * j2]; a.y = b_rnn[2 * j2 + 1];
            acc[j2] = a;
        }
        const v2f* er = (const v2f*)(embL + v * En);  // 25 x float2, 8B aligned
        #pragma unroll 5
        for (int k2 = 0; k2 < En / 2; ++k2) {
            v2f e2 = er[k2];
            v2f ex = {e2.x, e2.x}, ey = {e2.y, e2.y};
            #pragma unroll
            for (int j2 = 0; j2 < 5; ++j2) {
                v2f w0; w0.x = Wx[(2 * k2) * Hn + 2 * j2];     w0.y = Wx[(2 * k2) * Hn + 2 * j2 + 1];
                v2f w1; w1.x = Wx[(2 * k2 + 1) * Hn + 2 * j2]; w1.y = Wx[(2 * k2 + 1) * Hn + 2 * j2 + 1];
                acc[j2] += ex * w0;
                acc[j2] += ey * w1;
            }
        }
        float* Pr = Pl + v * PROW;
        #pragma unroll
        for (int j2 = 0; j2 < 5; ++j2) {
            Pr[2 * j2]     = acc[j2].x * LAMBDA;  // lambda folded into P
            Pr[2 * j2 + 1] = acc[j2].y * LAMBDA;
        }
        Pr[10] = 0.f;
        Pr[11] = 0.f;
    }

    // ---- Per-lane Wh fragments (L2-resident scalar loads), x LAMBDA ----
    const int g  = blockIdx.x * 256 + tid;
    const int b  = g >> 2;   // batch element
    const int q  = g & 3;    // quad sub-lane
    const int j0 = 3 * q;    // first owned hidden unit

    v2f   whv[4][3];
    float whs[4][3];
    #pragma unroll
    for (int m = 0; m < 4; ++m) {
        int qs = q ^ m;
        #pragma unroll
        for (int rp = 0; rp < 3; ++rp) {
            int js  = 3 * qs + rp;
            int jss = js < Hn ? js : 0;  // safe address, value zeroed below
            float w0 = Wh[jss * Hn + (j0 + 0 < Hn ? j0 + 0 : 0)];
            float w1 = Wh[jss * Hn + (j0 + 1 < Hn ? j0 + 1 : 0)];
            float w2 = Wh[jss * Hn + (j0 + 2 < Hn ? j0 + 2 : 0)];
            bool oks = js < Hn;
            v2f wv;
            wv.x = (oks && j0 + 0 < Hn) ? w0 * LAMBDA : 0.f;
            wv.y = (oks && j0 + 1 < Hn) ? w1 * LAMBDA : 0.f;
            whv[m][rp] = wv;
            whs[m][rp] = (oks && j0 + 2 < Hn) ? w2 * LAMBDA : 0.f;
        }
    }
    __syncthreads();

    // ---- Phase B: the recurrence (h is the true tanh output, unscaled;
    //      the lambda scale rides on P and the Wh fragments). ----
    const int* xb = x + b * Tn;  // 400 B/row -> 16B aligned

    v2f   hv = {0.f, 0.f};  // owned h: j0, j0+1
    float hs = 0.f;         // owned h: j0+2

    int4 xi = *(const int4*)xb;
    for (int c = 0; c < Tn / 4; ++c) {
        int4 xin = (c + 1 < Tn / 4) ? ((const int4*)xb)[c + 1] : xi;
        int xs[4] = {xi.x, xi.y, xi.z, xi.w};
        #pragma unroll
        for (int u = 0; u < 4; ++u) {
            const float* Pr = &Pl[xs[u] * PROW + j0];
            v2f pv;
            pv.x = Pr[0];
            pv.y = Pr[1];
            float ps = Pr[2];

            // Gather the full h vector from the quad via DPP (9 ops).
            float hsrc[4][3];
            hsrc[0][0] = hv.x;              hsrc[0][1] = hv.y;              hsrc[0][2] = hs;
            hsrc[1][0] = DPPF(hv.x, QP_X1); hsrc[1][1] = DPPF(hv.y, QP_X1); hsrc[1][2] = DPPF(hs, QP_X1);
            hsrc[2][0] = DPPF(hv.x, QP_X2); hsrc[2][1] = DPPF(hv.y, QP_X2); hsrc[2][2] = DPPF(hs, QP_X2);
            hsrc[3][0] = DPPF(hv.x, QP_X3); hsrc[3][1] = DPPF(hv.y, QP_X3); hsrc[3][2] = DPPF(hs, QP_X3);

            #pragma unroll
            for (int m = 0; m < 4; ++m)
                #pragma unroll
                for (int rp = 0; rp < 3; ++rp) {
                    v2f hb = {hsrc[m][rp], hsrc[m][rp]};
                    pv += hb * whv[m][rp];
                    ps = __builtin_fmaf(hsrc[m][rp], whs[m][rp], ps);
                }

            hv.x = tanh_scaled(pv.x);
            hv.y = tanh_scaled(pv.y);
            hs   = tanh_scaled(ps);
        }
        xi = xin;
    }

    // ---- Epilogue: dropout, quad-gather hd, dense over this lane's l-slice ----
    float hd[3];
    {
        float hown[3] = {hv.x, hv.y, hs};
        #pragma unroll
        for (int r = 0; r < 3; ++r) {
            int j   = j0 + r;
            int jdi = b * Hn + (j < Hn ? j : Hn - 1);  // safe address
            float d = drop[jdi];
            hd[r] = (j < Hn) ? hown[r] * d : 0.f;
        }
    }
    float hdsrc[4][3];
    hdsrc[0][0] = hd[0];              hdsrc[0][1] = hd[1];              hdsrc[0][2] = hd[2];
    hdsrc[1][0] = DPPF(hd[0], QP_X1); hdsrc[1][1] = DPPF(hd[1], QP_X1); hdsrc[1][2] = DPPF(hd[2], QP_X1);
    hdsrc[2][0] = DPPF(hd[0], QP_X2); hdsrc[2][1] = DPPF(hd[1], QP_X2); hdsrc[2][2] = DPPF(hd[2], QP_X2);
    hdsrc[3][0] = DPPF(hd[0], QP_X3); hdsrc[3][1] = DPPF(hd[1], QP_X3); hdsrc[3][2] = DPPF(hd[2], QP_X3);

    const int l0   = q * 4;
    const int lcnt = (q == 3) ? 3 : 4;
    #pragma unroll
    for (int li = 0; li < 4; ++li) {
        if (li >= lcnt) break;
        int l = l0 + li;
        float acc = bd[l];
        #pragma unroll
        for (int m = 0; m < 4; ++m)
            #pragma unroll
            for (int rp = 0; rp < 3; ++rp) {
                int js  = 3 * (q ^ m) + rp;
                int jss = js < Hn ? js : 0;  // hdsrc is 0 for pads
                acc = __builtin_fmaf(hdsrc[m][rp], Wd[jss * Ln + l], acc);
            }
        out[b * Ln + l] = acc;
    }
}

extern "C" void kernel_launch(void* const* d_in, const int* in_sizes, int n_in,
                              void* d_out, int out_size, void* d_ws, size_t ws_size,
                              hipStream_t stream) {
    const int*   x      = (const int*)d_in[0];
    const float* emb    = (const float*)d_in[1];
    const float* Wx     = (const float*)d_in[2];
    const float* Wh     = (const float*)d_in[3];
    const float* b_rnn  = (const float*)d_in[4];
    const float* Wd     = (const float*)d_in[5];
    const float* bd     = (const float*)d_in[6];
    const float* drop   = (const float*)d_in[7];
    float*       out    = (float*)d_out;
    (void)d_ws; (void)ws_size;

    // 65536 lanes / 256 = 256 blocks -> 1 block/CU, 4 waves -> 1 wave/SIMD.
    rnn_fused<<<(Bn * 4) / 256, 256, 0, stream>>>(x, emb, Wx, b_rnn, Wh, Wd, bd, drop, out);
}